// Round 9
// baseline (313.058 us; speedup 1.0000x reference)
//
#include <hip/hip_runtime.h>

#define LP 400
#define LQ 50
#define BZ 32
#define SZ 768
#define HH 128
#define PR_TOT 14400   // 12800 Up rows + 1600 Uq rows; 225 x 64 exact
#define NZ 4           // K-split factor (768/4 = 192 per split)

typedef unsigned short u16;
typedef __attribute__((ext_vector_type(8))) short short8;
typedef __attribute__((ext_vector_type(4))) float f32x4;

__device__ __forceinline__ float fexp2(float x) {
#if __has_builtin(__builtin_amdgcn_exp2f)
  return __builtin_amdgcn_exp2f(x);
#else
  return exp2f(x);
#endif
}
__device__ __forceinline__ float frcp(float x) {
#if __has_builtin(__builtin_amdgcn_rcpf)
  return __builtin_amdgcn_rcpf(x);
#else
  return 1.0f / x;
#endif
}

__device__ __forceinline__ unsigned pack2(float x, float y) {
  return (__float_as_uint(x) >> 16) | (__float_as_uint(y) & 0xffff0000u);
}
__device__ __forceinline__ float remf(float x) {
  return x - __uint_as_float(__float_as_uint(x) & 0xffff0000u);
}

// K0: fused prep. Blocks 0..95: split Wp_w/Wq_w into hi/lo bf16 planes.
//     Blocks 96..111: Wvv[b][g] = Wv_b[g] + sum_h v[b][h]*Wv_w[g][h].
__global__ __launch_bounds__(256) void prep_kernel(
    const float* __restrict__ Wp_w, const float* __restrict__ Wq_w,
    const float* __restrict__ v, const float* __restrict__ Wv_w,
    const float* __restrict__ Wv_b,
    u16* __restrict__ Wph, u16* __restrict__ Wpl,
    u16* __restrict__ Wqh, u16* __restrict__ Wql, float* __restrict__ Wvv) {
  const int bx = blockIdx.x, t = threadIdx.x;
  if (bx < 96) {
    int gid = bx * 256 + t;
    int base = gid * 8;
    const float* src;
    u16 *dh, *dl;
    if (base < HH * SZ) {
      src = Wp_w + base; dh = Wph + base; dl = Wpl + base;
    } else {
      int o = base - HH * SZ;
      src = Wq_w + o; dh = Wqh + o; dl = Wql + o;
    }
    float4 x0 = *(const float4*)src;
    float4 x1 = *(const float4*)(src + 4);
    uint4 H, L;
    H.x = pack2(x0.x, x0.y); H.y = pack2(x0.z, x0.w);
    H.z = pack2(x1.x, x1.y); H.w = pack2(x1.z, x1.w);
    L.x = pack2(remf(x0.x), remf(x0.y)); L.y = pack2(remf(x0.z), remf(x0.w));
    L.z = pack2(remf(x1.x), remf(x1.y)); L.w = pack2(remf(x1.z), remf(x1.w));
    *(uint4*)dh = H;
    *(uint4*)dl = L;
  } else {
    int id = (bx - 96) * 256 + t;
    int b = id >> 7, g = id & 127;
    const float4* vb = reinterpret_cast<const float4*>(v + b * HH);
    const float4* wr = reinterpret_cast<const float4*>(Wv_w + g * HH);
    float s = Wv_b[g];
#pragma unroll
    for (int i = 0; i < HH / 4; ++i) {
      float4 a = vb[i], w = wr[i];
      s = fmaf(a.x, w.x, s); s = fmaf(a.y, w.y, s);
      s = fmaf(a.z, w.z, s); s = fmaf(a.w, w.w, s);
    }
    Wvv[id] = s;
  }
}

// K1: split-bf16 MFMA GEMM. Rows = [Up | Uq], N=128, K split in NZ=4 (z: 192 each).
// BM=64, grid (225, 4) = 900 blocks (~3.5/CU). 4 waves 2x2, wave tile 32x64.
__global__ __launch_bounds__(256, 2) void mfma_gemm(
    const float* __restrict__ Up, const float* __restrict__ Uq,
    const u16* __restrict__ Wph, const u16* __restrict__ Wpl,
    const u16* __restrict__ Wqh, const u16* __restrict__ Wql,
    float* __restrict__ partial) {
  __shared__ u16 Ah[64][40], Al[64][40], Bh[128][40], Bl[128][40];
  const int t = threadIdx.x, lane = t & 63, wid = t >> 6;
  const int bx = blockIdx.x, z = blockIdx.y;
  const int m0 = bx * 64;
  const bool probq = (bx >= 200);
  const u16* WH = probq ? Wqh : Wph;
  const u16* WL = probq ? Wql : Wpl;
  const int k0base = z * 192;

  const int ra = t >> 1, kh = (t & 1) * 16;
  const bool hasA = (ra < 64);  // wave-uniform: waves 0,1 stage A
  const int grow = m0 + (ra & 63);
  const float* srcA = (grow < 12800) ? (Up + (size_t)grow * SZ)
                                     : (Uq + (size_t)(grow - 12800) * SZ);
  const u16* srcWH = WH + ra * SZ;
  const u16* srcWL = WL + ra * SZ;

  const int wm = (wid >> 1) * 32, wn = (wid & 1) * 64;
  const int fr = lane & 15, fg = lane >> 4;

  f32x4 acc[2][4];
#pragma unroll
  for (int i = 0; i < 2; ++i)
#pragma unroll
    for (int j = 0; j < 4; ++j) acc[i][j] = (f32x4){0.f, 0.f, 0.f, 0.f};

  float4 a0, a1, a2, a3;
  uint4 wh0, wh1, wl0, wl1;

#define GLOAD(s)                                                         \
  do {                                                                   \
    int kk = k0base + (s) * 32 + kh;                                     \
    if (hasA) {                                                          \
      a0 = *(const float4*)(srcA + kk);                                  \
      a1 = *(const float4*)(srcA + kk + 4);                              \
      a2 = *(const float4*)(srcA + kk + 8);                              \
      a3 = *(const float4*)(srcA + kk + 12);                             \
    }                                                                    \
    wh0 = *(const uint4*)(srcWH + kk); wh1 = *(const uint4*)(srcWH + kk + 8); \
    wl0 = *(const uint4*)(srcWL + kk); wl1 = *(const uint4*)(srcWL + kk + 8); \
  } while (0)

#define WSTORE()                                                          \
  do {                                                                    \
    if (hasA) {                                                           \
      uint4 H0, H1, L0, L1;                                               \
      H0.x = pack2(a0.x, a0.y); H0.y = pack2(a0.z, a0.w);                 \
      H0.z = pack2(a1.x, a1.y); H0.w = pack2(a1.z, a1.w);                 \
      H1.x = pack2(a2.x, a2.y); H1.y = pack2(a2.z, a2.w);                 \
      H1.z = pack2(a3.x, a3.y); H1.w = pack2(a3.z, a3.w);                 \
      L0.x = pack2(remf(a0.x), remf(a0.y)); L0.y = pack2(remf(a0.z), remf(a0.w)); \
      L0.z = pack2(remf(a1.x), remf(a1.y)); L0.w = pack2(remf(a1.z), remf(a1.w)); \
      L1.x = pack2(remf(a2.x), remf(a2.y)); L1.y = pack2(remf(a2.z), remf(a2.w)); \
      L1.z = pack2(remf(a3.x), remf(a3.y)); L1.w = pack2(remf(a3.z), remf(a3.w)); \
      *(uint4*)&Ah[ra][kh] = H0; *(uint4*)&Ah[ra][kh + 8] = H1;           \
      *(uint4*)&Al[ra][kh] = L0; *(uint4*)&Al[ra][kh + 8] = L1;           \
    }                                                                     \
    *(uint4*)&Bh[ra][kh] = wh0; *(uint4*)&Bh[ra][kh + 8] = wh1;           \
    *(uint4*)&Bl[ra][kh] = wl0; *(uint4*)&Bl[ra][kh + 8] = wl1;           \
  } while (0)

  GLOAD(0);
  WSTORE();
  __syncthreads();

  for (int s = 0; s < 6; ++s) {
    if (s < 5) GLOAD(s + 1);  // reg prefetch: HBM latency hides under MFMA (T14)
    short8 ah[2], al[2], bh[4], bl[4];
#pragma unroll
    for (int i = 0; i < 2; ++i) {
      ah[i] = *(const short8*)&Ah[wm + i * 16 + fr][fg * 8];
      al[i] = *(const short8*)&Al[wm + i * 16 + fr][fg * 8];
    }
#pragma unroll
    for (int j = 0; j < 4; ++j) {
      bh[j] = *(const short8*)&Bh[wn + j * 16 + fr][fg * 8];
      bl[j] = *(const short8*)&Bl[wn + j * 16 + fr][fg * 8];
    }
#pragma unroll
    for (int i = 0; i < 2; ++i)
#pragma unroll
      for (int j = 0; j < 4; ++j) {
        acc[i][j] = __builtin_amdgcn_mfma_f32_16x16x32_bf16(ah[i], bh[j], acc[i][j], 0, 0, 0);
        acc[i][j] = __builtin_amdgcn_mfma_f32_16x16x32_bf16(ah[i], bl[j], acc[i][j], 0, 0, 0);
        acc[i][j] = __builtin_amdgcn_mfma_f32_16x16x32_bf16(al[i], bh[j], acc[i][j], 0, 0, 0);
      }
    __syncthreads();
    if (s < 5) WSTORE();
    __syncthreads();
  }
#undef GLOAD
#undef WSTORE

  float* pz = partial + (size_t)z * (PR_TOT * HH);
#pragma unroll
  for (int i = 0; i < 2; ++i) {
    int r0 = m0 + wm + i * 16 + fg * 4;
#pragma unroll
    for (int j = 0; j < 4; ++j) {
      int c = wn + j * 16 + fr;
#pragma unroll
      for (int e = 0; e < 4; ++e) pz[(size_t)(r0 + e) * HH + c] = acc[i][j][e];
    }
  }
}

// K2: score + softmax -> aw. Block = 16 p x 1 b, 256 thr (4 waves x 4 p), 800 blocks.
// Staging folds the NZ-way K-split reduce (+bias,*TS); W2 transposed [h][q] so
// lane-q reads are stride-1 (conflict-free). s~[q] = -2*sum_h v[h]*rcp(exp2+1)
// (sum_h v term softmax-shift-invariant, dropped). XCD swizzle: 25 p-blocks of
// each b pinned to one XCD (Uq/W2 slices stay in that L2).
__global__ __launch_bounds__(256, 4) void score_kernel(
    const float* __restrict__ partial, const float* __restrict__ Wp_b,
    const float* __restrict__ Wq_b, const float* __restrict__ Wvv,
    const float* __restrict__ v, float* __restrict__ aw, float TS) {
  const int f = blockIdx.x;  // 0..799
  const int xcd = f & 7, j = f >> 3;
  const int b = xcd * 4 + j / 25;
  const int pbase = (j % 25) * 16;
  const int t = threadIdx.x, lane = t & 63, w = t >> 6;
  __shared__ float W2s[HH][52];
  __shared__ f32x4 Wps4[16][32];
  __shared__ f32x4 vsh4[32];

  for (int ff = t; ff < LQ * 32; ff += 256) {
    int q_ = ff % LQ, c4 = ff / LQ;
    size_t row = 12800 + (size_t)(q_ * BZ + b);
    const float* pp = &partial[row * HH + c4 * 4];
    float4 p0 = *(const float4*)pp;
    float4 p1 = *(const float4*)(pp + (size_t)PR_TOT * HH);
    float4 p2 = *(const float4*)(pp + (size_t)2 * PR_TOT * HH);
    float4 p3 = *(const float4*)(pp + (size_t)3 * PR_TOT * HH);
    float4 bb = *(const float4*)&Wq_b[c4 * 4];
    float4 wv = *(const float4*)&Wvv[b * HH + c4 * 4];
    W2s[c4 * 4 + 0][q_] = (p0.x + p1.x + p2.x + p3.x + bb.x + wv.x) * TS;
    W2s[c4 * 4 + 1][q_] = (p0.y + p1.y + p2.y + p3.y + bb.y + wv.y) * TS;
    W2s[c4 * 4 + 2][q_] = (p0.z + p1.z + p2.z + p3.z + bb.z + wv.z) * TS;
    W2s[c4 * 4 + 3][q_] = (p0.w + p1.w + p2.w + p3.w + bb.w + wv.w) * TS;
  }
#pragma unroll
  for (int rep = 0; rep < 2; ++rep) {  // Wps: 16 rows x 32 c4 = 512 slots
    int ff = t + rep * 256;
    int i = ff >> 5, c4 = ff & 31;
    size_t grow = (size_t)(pbase + i) * BZ + b;
    const float* pp = &partial[grow * HH + c4 * 4];
    float4 p0 = *(const float4*)pp;
    float4 p1 = *(const float4*)(pp + (size_t)PR_TOT * HH);
    float4 p2 = *(const float4*)(pp + (size_t)2 * PR_TOT * HH);
    float4 p3 = *(const float4*)(pp + (size_t)3 * PR_TOT * HH);
    float4 bb = *(const float4*)&Wp_b[c4 * 4];
    Wps4[i][c4] = (f32x4){(p0.x + p1.x + p2.x + p3.x + bb.x) * TS,
                          (p0.y + p1.y + p2.y + p3.y + bb.y) * TS,
                          (p0.z + p1.z + p2.z + p3.z + bb.z) * TS,
                          (p0.w + p1.w + p2.w + p3.w + bb.w) * TS};
  }
  if (t < 32) {
    float4 x = *(const float4*)&v[b * HH + t * 4];
    vsh4[t] = (f32x4){x.x, x.y, x.z, x.w};
  }
  __syncthreads();

  const int q = (lane < LQ) ? lane : (LQ - 1);
  const int prow = w * 4;
  float A0 = 0.f, A1 = 0.f, A2 = 0.f, A3 = 0.f;
  for (int h4 = 0; h4 < 32; ++h4) {
    f32x4 vj = vsh4[h4];
    f32x4 w0 = Wps4[prow + 0][h4];
    f32x4 w1 = Wps4[prow + 1][h4];
    f32x4 w2 = Wps4[prow + 2][h4];
    f32x4 w3 = Wps4[prow + 3][h4];
    float s0 = W2s[h4 * 4 + 0][q];
    float s1 = W2s[h4 * 4 + 1][q];
    float s2 = W2s[h4 * 4 + 2][q];
    float s3 = W2s[h4 * 4 + 3][q];
    A0 = fmaf(vj[0], frcp(fexp2(w0[0] + s0) + 1.f), A0);
    A0 = fmaf(vj[1], frcp(fexp2(w0[1] + s1) + 1.f), A0);
    A0 = fmaf(vj[2], frcp(fexp2(w0[2] + s2) + 1.f), A0);
    A0 = fmaf(vj[3], frcp(fexp2(w0[3] + s3) + 1.f), A0);
    A1 = fmaf(vj[0], frcp(fexp2(w1[0] + s0) + 1.f), A1);
    A1 = fmaf(vj[1], frcp(fexp2(w1[1] + s1) + 1.f), A1);
    A1 = fmaf(vj[2], frcp(fexp2(w1[2] + s2) + 1.f), A1);
    A1 = fmaf(vj[3], frcp(fexp2(w1[3] + s3) + 1.f), A1);
    A2 = fmaf(vj[0], frcp(fexp2(w2[0] + s0) + 1.f), A2);
    A2 = fmaf(vj[1], frcp(fexp2(w2[1] + s1) + 1.f), A2);
    A2 = fmaf(vj[2], frcp(fexp2(w2[2] + s2) + 1.f), A2);
    A2 = fmaf(vj[3], frcp(fexp2(w2[3] + s3) + 1.f), A2);
    A3 = fmaf(vj[0], frcp(fexp2(w3[0] + s0) + 1.f), A3);
    A3 = fmaf(vj[1], frcp(fexp2(w3[1] + s1) + 1.f), A3);
    A3 = fmaf(vj[2], frcp(fexp2(w3[2] + s2) + 1.f), A3);
    A3 = fmaf(vj[3], frcp(fexp2(w3[3] + s3) + 1.f), A3);
  }

#define SOFTMAX(AR, PI)                                                   \
  do {                                                                    \
    float a = (lane < LQ) ? (AR) : 1e30f;                                 \
    float mn = a;                                                         \
    mn = fminf(mn, __shfl_xor(mn, 1));  mn = fminf(mn, __shfl_xor(mn, 2)); \
    mn = fminf(mn, __shfl_xor(mn, 4));  mn = fminf(mn, __shfl_xor(mn, 8)); \
    mn = fminf(mn, __shfl_xor(mn, 16)); mn = fminf(mn, __shfl_xor(mn, 32)); \
    float e = fexp2((mn - a) * TS); /* lanes>=50: exp2(-huge)=0 */        \
    float sm = e;                                                         \
    sm += __shfl_xor(sm, 1);  sm += __shfl_xor(sm, 2);                    \
    sm += __shfl_xor(sm, 4);  sm += __shfl_xor(sm, 8);                    \
    sm += __shfl_xor(sm, 16); sm += __shfl_xor(sm, 32);                   \
    float val = e * frcp(sm);                                             \
    if (lane < LQ)                                                        \
      aw[(size_t)((pbase + prow + (PI)) * BZ + b) * LQ + lane] = val;     \
  } while (0)

  SOFTMAX(A0, 0); SOFTMAX(A1, 1); SOFTMAX(A2, 2); SOFTMAX(A3, 3);
#undef SOFTMAX
}

// K3: ctx: out[p,b,s] = sum_q aw[p,b,q]*Uq[q,b,s]. Block = 16 p x 1 b, 192 thr,
// thread owns float4 of s; as_ LDS 3.3 KB -> ~6 blocks/CU. Same XCD swizzle.
__global__ __launch_bounds__(192, 5) void ctx_kernel(
    const float* __restrict__ aw, const float* __restrict__ Uq,
    float* __restrict__ out) {
  const int f = blockIdx.x;  // 0..799
  const int xcd = f & 7, j = f >> 3;
  const int b = xcd * 4 + j / 25;
  const int pbase = (j % 25) * 16;
  const int t = threadIdx.x;
  __shared__ float as_[16][52];
  for (int ff = t; ff < 16 * LQ; ff += 192) {
    int i = ff / LQ, qq = ff - i * LQ;
    as_[i][qq] = aw[(size_t)((pbase + i) * BZ + b) * LQ + qq];
  }
  __syncthreads();
  const int s4 = t * 4;
  f32x4 acc[16];
#pragma unroll
  for (int i = 0; i < 16; ++i) acc[i] = (f32x4){0.f, 0.f, 0.f, 0.f};
  for (int qp = 0; qp < LQ; qp += 2) {
    float4 u0 = *(const float4*)&Uq[(size_t)(qp * BZ + b) * SZ + s4];
    float4 u1 = *(const float4*)&Uq[(size_t)((qp + 1) * BZ + b) * SZ + s4];
#pragma unroll
    for (int i = 0; i < 16; ++i) {
      float2 a2 = *(const float2*)&as_[i][qp];
      acc[i][0] = fmaf(a2.x, u0.x, acc[i][0]); acc[i][1] = fmaf(a2.x, u0.y, acc[i][1]);
      acc[i][2] = fmaf(a2.x, u0.z, acc[i][2]); acc[i][3] = fmaf(a2.x, u0.w, acc[i][3]);
      acc[i][0] = fmaf(a2.y, u1.x, acc[i][0]); acc[i][1] = fmaf(a2.y, u1.y, acc[i][1]);
      acc[i][2] = fmaf(a2.y, u1.z, acc[i][2]); acc[i][3] = fmaf(a2.y, u1.w, acc[i][3]);
    }
  }
#pragma unroll
  for (int i = 0; i < 16; ++i) {
    float4 r = make_float4(acc[i][0], acc[i][1], acc[i][2], acc[i][3]);
    *(float4*)&out[(size_t)((pbase + i) * BZ + b) * SZ + s4] = r;
  }
}

extern "C" void kernel_launch(void* const* d_in, const int* in_sizes, int n_in,
                              void* d_out, int out_size, void* d_ws, size_t ws_size,
                              hipStream_t stream) {
  const float* Up   = (const float*)d_in[0];
  const float* Uq   = (const float*)d_in[1];
  const float* Wp_w = (const float*)d_in[2];
  const float* Wp_b = (const float*)d_in[3];
  const float* Wq_w = (const float*)d_in[4];
  const float* Wq_b = (const float*)d_in[5];
  const float* Wv_w = (const float*)d_in[6];
  const float* Wv_b = (const float*)d_in[7];
  const float* v    = (const float*)d_in[8];
  float* out = (float*)d_out;

  // workspace ~33 MB: partials must not alias d_out (score reads them while
  // ctx writes out in a later dispatch, but aw/partial persist across kernels).
  float* ws      = (float*)d_ws;
  float* Wvv     = ws;                        // 32*128 = 4096 f
  float* aw      = Wvv + BZ * HH;             // 12800*50 = 640000 f
  u16* Wph       = (u16*)(aw + LP * BZ * LQ); // 4 planes x 98304 u16
  u16* Wpl       = Wph + HH * SZ;
  u16* Wqh       = Wpl + HH * SZ;
  u16* Wql       = Wqh + HH * SZ;
  float* partial = (float*)(Wql + HH * SZ);   // NZ x 14400 x 128 f = 29.5 MB

  const float TS = 2.8853900817779268f;  // 2*log2(e)

  prep_kernel<<<dim3(112), dim3(256), 0, stream>>>(
      Wp_w, Wq_w, v, Wv_w, Wv_b, Wph, Wpl, Wqh, Wql, Wvv);
  mfma_gemm<<<dim3(225, NZ), dim3(256), 0, stream>>>(
      Up, Uq, Wph, Wpl, Wqh, Wql, partial);
  score_kernel<<<dim3(800), dim3(256), 0, stream>>>(
      partial, Wp_b, Wq_b, Wvv, v, aw, TS);
  ctx_kernel<<<dim3(800), dim3(192), 0, stream>>>(aw, Uq, out);
}

// Round 10
// 204.414 us; speedup vs baseline: 1.5315x; 1.5315x over previous
//
#include <hip/hip_runtime.h>

#define LP 400
#define LQ 50
#define BZ 32
#define SZ 768
#define HH 128
#define NZ 4  // Uq-projection K-split (768/4 = 192 per z)

typedef unsigned short u16;
typedef __attribute__((ext_vector_type(8))) short short8;
typedef __attribute__((ext_vector_type(4))) float f32x4;

__device__ __forceinline__ float fexp2(float x) {
#if __has_builtin(__builtin_amdgcn_exp2f)
  return __builtin_amdgcn_exp2f(x);
#else
  return exp2f(x);
#endif
}
__device__ __forceinline__ float frcp(float x) {
#if __has_builtin(__builtin_amdgcn_rcpf)
  return __builtin_amdgcn_rcpf(x);
#else
  return 1.0f / x;
#endif
}

__device__ __forceinline__ unsigned pack2(float x, float y) {
  return (__float_as_uint(x) >> 16) | (__float_as_uint(y) & 0xffff0000u);
}
__device__ __forceinline__ float remf(float x) {
  return x - __uint_as_float(__float_as_uint(x) & 0xffff0000u);
}

// K0: fused prep. Blocks 0..95: split Wp_w/Wq_w into hi/lo truncated-bf16 planes.
//     Blocks 96..111: Wvv[b][g] = Wv_b[g] + sum_h v[b][h]*Wv_w[g][h].
__global__ __launch_bounds__(256) void prep_kernel(
    const float* __restrict__ Wp_w, const float* __restrict__ Wq_w,
    const float* __restrict__ v, const float* __restrict__ Wv_w,
    const float* __restrict__ Wv_b,
    u16* __restrict__ Wph, u16* __restrict__ Wpl,
    u16* __restrict__ Wqh, u16* __restrict__ Wql, float* __restrict__ Wvv) {
  const int bx = blockIdx.x, t = threadIdx.x;
  if (bx < 96) {
    int gid = bx * 256 + t;
    int base = gid * 8;
    const float* src;
    u16 *dh, *dl;
    if (base < HH * SZ) {
      src = Wp_w + base; dh = Wph + base; dl = Wpl + base;
    } else {
      int o = base - HH * SZ;
      src = Wq_w + o; dh = Wqh + o; dl = Wql + o;
    }
    float4 x0 = *(const float4*)src;
    float4 x1 = *(const float4*)(src + 4);
    uint4 H, L;
    H.x = pack2(x0.x, x0.y); H.y = pack2(x0.z, x0.w);
    H.z = pack2(x1.x, x1.y); H.w = pack2(x1.z, x1.w);
    L.x = pack2(remf(x0.x), remf(x0.y)); L.y = pack2(remf(x0.z), remf(x0.w));
    L.z = pack2(remf(x1.x), remf(x1.y)); L.w = pack2(remf(x1.z), remf(x1.w));
    *(uint4*)dh = H;
    *(uint4*)dl = L;
  } else {
    int id = (bx - 96) * 256 + t;
    int b = id >> 7, g = id & 127;
    const float4* vb = reinterpret_cast<const float4*>(v + b * HH);
    const float4* wr = reinterpret_cast<const float4*>(Wv_w + g * HH);
    float s = Wv_b[g];
#pragma unroll
    for (int i = 0; i < HH / 4; ++i) {
      float4 a = vb[i], w = wr[i];
      s = fmaf(a.x, w.x, s); s = fmaf(a.y, w.y, s);
      s = fmaf(a.z, w.z, s); s = fmaf(a.w, w.w, s);
    }
    Wvv[id] = s;
  }
}

// K1: Uq-projection split-bf16 MFMA GEMM: 1600 rows x 128, K split NZ=4.
// BM=64, grid (25, NZ). Proven r7 structure (BM64 wave tile 32x64, [*][40] LDS).
// Raw partial sums out (bias/Wvv/TS folded in later by mega's W2 staging).
__global__ __launch_bounds__(256, 2) void w2_gemm(
    const float* __restrict__ Uq, const u16* __restrict__ Wqh,
    const u16* __restrict__ Wql, float* __restrict__ partialW2) {
  __shared__ u16 Ah[64][40], Al[64][40], Bh[128][40], Bl[128][40];
  const int t = threadIdx.x, lane = t & 63, wid = t >> 6;
  const int bx = blockIdx.x, z = blockIdx.y;
  const int m0 = bx * 64;
  const int k0base = z * 192;
  const int ra = t >> 1, kh = (t & 1) * 16;
  const bool hasA = (ra < 64);  // wave-uniform: waves 0,1 stage A
  const int grow = m0 + (ra & 63);  // < 1600 always
  const float* srcA = Uq + (size_t)grow * SZ;
  const u16* srcWH = Wqh + ra * SZ;
  const u16* srcWL = Wql + ra * SZ;
  const int wm = (wid >> 1) * 32, wn = (wid & 1) * 64;
  const int fr = lane & 15, fg = lane >> 4;

  f32x4 acc[2][4];
#pragma unroll
  for (int i = 0; i < 2; ++i)
#pragma unroll
    for (int j = 0; j < 4; ++j) acc[i][j] = (f32x4){0.f, 0.f, 0.f, 0.f};

  float4 a0, a1, a2, a3;
  uint4 wh0, wh1, wl0, wl1;

#define GLOAD(s)                                                         \
  do {                                                                   \
    int kk = k0base + (s) * 32 + kh;                                     \
    if (hasA) {                                                          \
      a0 = *(const float4*)(srcA + kk);                                  \
      a1 = *(const float4*)(srcA + kk + 4);                              \
      a2 = *(const float4*)(srcA + kk + 8);                              \
      a3 = *(const float4*)(srcA + kk + 12);                             \
    }                                                                    \
    wh0 = *(const uint4*)(srcWH + kk); wh1 = *(const uint4*)(srcWH + kk + 8); \
    wl0 = *(const uint4*)(srcWL + kk); wl1 = *(const uint4*)(srcWL + kk + 8); \
  } while (0)

#define WSTORE()                                                          \
  do {                                                                    \
    if (hasA) {                                                           \
      uint4 H0, H1, L0, L1;                                               \
      H0.x = pack2(a0.x, a0.y); H0.y = pack2(a0.z, a0.w);                 \
      H0.z = pack2(a1.x, a1.y); H0.w = pack2(a1.z, a1.w);                 \
      H1.x = pack2(a2.x, a2.y); H1.y = pack2(a2.z, a2.w);                 \
      H1.z = pack2(a3.x, a3.y); H1.w = pack2(a3.z, a3.w);                 \
      L0.x = pack2(remf(a0.x), remf(a0.y)); L0.y = pack2(remf(a0.z), remf(a0.w)); \
      L0.z = pack2(remf(a1.x), remf(a1.y)); L0.w = pack2(remf(a1.z), remf(a1.w)); \
      L1.x = pack2(remf(a2.x), remf(a2.y)); L1.y = pack2(remf(a2.z), remf(a2.w)); \
      L1.z = pack2(remf(a3.x), remf(a3.y)); L1.w = pack2(remf(a3.z), remf(a3.w)); \
      *(uint4*)&Ah[ra][kh] = H0; *(uint4*)&Ah[ra][kh + 8] = H1;           \
      *(uint4*)&Al[ra][kh] = L0; *(uint4*)&Al[ra][kh + 8] = L1;           \
    }                                                                     \
    *(uint4*)&Bh[ra][kh] = wh0; *(uint4*)&Bh[ra][kh + 8] = wh1;           \
    *(uint4*)&Bl[ra][kh] = wl0; *(uint4*)&Bl[ra][kh + 8] = wl1;           \
  } while (0)

  GLOAD(0);
  WSTORE();
  __syncthreads();

  for (int s = 0; s < 6; ++s) {
    if (s < 5) GLOAD(s + 1);
    short8 ah[2], al[2], bh[4], bl[4];
#pragma unroll
    for (int i = 0; i < 2; ++i) {
      ah[i] = *(const short8*)&Ah[wm + i * 16 + fr][fg * 8];
      al[i] = *(const short8*)&Al[wm + i * 16 + fr][fg * 8];
    }
#pragma unroll
    for (int j = 0; j < 4; ++j) {
      bh[j] = *(const short8*)&Bh[wn + j * 16 + fr][fg * 8];
      bl[j] = *(const short8*)&Bl[wn + j * 16 + fr][fg * 8];
    }
#pragma unroll
    for (int i = 0; i < 2; ++i)
#pragma unroll
      for (int j = 0; j < 4; ++j) {
        acc[i][j] = __builtin_amdgcn_mfma_f32_16x16x32_bf16(ah[i], bh[j], acc[i][j], 0, 0, 0);
        acc[i][j] = __builtin_amdgcn_mfma_f32_16x16x32_bf16(ah[i], bl[j], acc[i][j], 0, 0, 0);
        acc[i][j] = __builtin_amdgcn_mfma_f32_16x16x32_bf16(al[i], bh[j], acc[i][j], 0, 0, 0);
      }
    __syncthreads();
    if (s < 5) WSTORE();
    __syncthreads();
  }
#undef GLOAD
#undef WSTORE

  float* pz = partialW2 + (size_t)z * (1600 * HH);
#pragma unroll
  for (int i = 0; i < 2; ++i) {
    int r0 = m0 + wm + i * 16 + fg * 4;
#pragma unroll
    for (int j = 0; j < 4; ++j) {
      int c = wn + j * 16 + fr;
#pragma unroll
      for (int e = 0; e < 4; ++e) pz[(size_t)(r0 + e) * HH + c] = acc[i][j][e];
    }
  }
}

// K2: MEGA — per block (16 p x 1 b, 800 blocks, 256 thr):
//  Phase A: project the block's 16 Up rows via split-bf16 MFMA (M=16, N=128,
//    K=768 in 24 BK=32 steps) -> Wps LDS (+Wp_b, *TS). Zero redundancy: 800x16
//    blocks/rows = all 12800 Up rows exactly once. No partial round-trip.
//  Phase B: stage W2s (reduce NZ partialW2 planes +Wq_b+Wvv, *TS, transposed
//    [h][q] -> lane-q reads stride-1), vsh; then score+softmax (r7-proven loop).
//  Phase C: ctx (r6-proven): out = sum_q as_[p][q]*Uq[q,b,s].
// Swizzle (r6, write-contiguity proven): b = low5(f) bijective, pbase outer ->
// concurrent blocks write one contiguous out slab; per-XCD b-sets keep Uq/W2 L2-hot.
__global__ __launch_bounds__(256, 4) void mega_kernel(
    const float* __restrict__ Up, const u16* __restrict__ Wph,
    const u16* __restrict__ Wpl, const float* __restrict__ partialW2,
    const float* __restrict__ Wp_b, const float* __restrict__ Wq_b,
    const float* __restrict__ Wvv, const float* __restrict__ v,
    const float* __restrict__ Uq, float* __restrict__ out, float TS) {
  union SMemU {  // GEMM staging (23 KB) and score/ctx buffers (30 KB) are
    struct { u16 Ah[16][40]; u16 Al[16][40]; u16 Bh[128][40]; u16 Bl[128][40]; } g;
    struct { float W2s[HH][52]; float as_[16][52]; float vsh[HH]; } s;
  };           // temporally disjoint -> union. Total LDS 38.9 KB -> 4 blocks/CU.
  __shared__ SMemU sm;
  __shared__ f32x4 Wps4[16][33];  // [p][h4], row 132 floats (pad -> 2-way banks)

  const int f = blockIdx.x;  // 0..799
  const int b = ((f & 7) << 2) | ((f >> 3) & 3);
  const int pbase = (f >> 5) * 16;
  const int t = threadIdx.x, lane = t & 63, wid = t >> 6;
  const int fr = lane & 15, fg = lane >> 4;

  // ---------- Phase A: Up projection ----------
  const int ra = t >> 1, kh = (t & 1) * 16;
  const bool hasA = (t < 32);          // 16 A rows staged by threads 0..31
  const int arn = (t >> 1) & 15;
  const float* srcA = Up + ((size_t)(pbase + arn) * BZ + b) * SZ;
  const u16* srcWH = Wph + ra * SZ;
  const u16* srcWL = Wpl + ra * SZ;
  const int n0 = wid * 32;             // wave owns N-tiles n0..n0+31

  f32x4 acc[2];
  acc[0] = (f32x4){0.f, 0.f, 0.f, 0.f};
  acc[1] = (f32x4){0.f, 0.f, 0.f, 0.f};
  float4 a0, a1, a2, a3;
  uint4 wh0, wh1, wl0, wl1;

#define MGLOAD(s)                                                        \
  do {                                                                   \
    int kk = (s) * 32 + kh;                                              \
    if (hasA) {                                                          \
      a0 = *(const float4*)(srcA + kk);                                  \
      a1 = *(const float4*)(srcA + kk + 4);                              \
      a2 = *(const float4*)(srcA + kk + 8);                              \
      a3 = *(const float4*)(srcA + kk + 12);                             \
    }                                                                    \
    wh0 = *(const uint4*)(srcWH + kk); wh1 = *(const uint4*)(srcWH + kk + 8); \
    wl0 = *(const uint4*)(srcWL + kk); wl1 = *(const uint4*)(srcWL + kk + 8); \
  } while (0)

#define MWSTORE()                                                         \
  do {                                                                    \
    if (hasA) {                                                           \
      uint4 H0, H1, L0, L1;                                               \
      H0.x = pack2(a0.x, a0.y); H0.y = pack2(a0.z, a0.w);                 \
      H0.z = pack2(a1.x, a1.y); H0.w = pack2(a1.z, a1.w);                 \
      H1.x = pack2(a2.x, a2.y); H1.y = pack2(a2.z, a2.w);                 \
      H1.z = pack2(a3.x, a3.y); H1.w = pack2(a3.z, a3.w);                 \
      L0.x = pack2(remf(a0.x), remf(a0.y)); L0.y = pack2(remf(a0.z), remf(a0.w)); \
      L0.z = pack2(remf(a1.x), remf(a1.y)); L0.w = pack2(remf(a1.z), remf(a1.w)); \
      L1.x = pack2(remf(a2.x), remf(a2.y)); L1.y = pack2(remf(a2.z), remf(a2.w)); \
      L1.z = pack2(remf(a3.x), remf(a3.y)); L1.w = pack2(remf(a3.z), remf(a3.w)); \
      *(uint4*)&sm.g.Ah[arn][kh] = H0; *(uint4*)&sm.g.Ah[arn][kh + 8] = H1; \
      *(uint4*)&sm.g.Al[arn][kh] = L0; *(uint4*)&sm.g.Al[arn][kh + 8] = L1; \
    }                                                                     \
    *(uint4*)&sm.g.Bh[ra][kh] = wh0; *(uint4*)&sm.g.Bh[ra][kh + 8] = wh1; \
    *(uint4*)&sm.g.Bl[ra][kh] = wl0; *(uint4*)&sm.g.Bl[ra][kh + 8] = wl1; \
  } while (0)

  MGLOAD(0);
  MWSTORE();
  __syncthreads();

  for (int s = 0; s < 24; ++s) {
    if (s < 23) MGLOAD(s + 1);  // reg prefetch hides HBM latency under MFMA (T14)
    short8 ah = *(const short8*)&sm.g.Ah[fr][fg * 8];
    short8 al = *(const short8*)&sm.g.Al[fr][fg * 8];
    short8 bh0 = *(const short8*)&sm.g.Bh[n0 + fr][fg * 8];
    short8 bl0 = *(const short8*)&sm.g.Bl[n0 + fr][fg * 8];
    short8 bh1 = *(const short8*)&sm.g.Bh[n0 + 16 + fr][fg * 8];
    short8 bl1 = *(const short8*)&sm.g.Bl[n0 + 16 + fr][fg * 8];
    acc[0] = __builtin_amdgcn_mfma_f32_16x16x32_bf16(ah, bh0, acc[0], 0, 0, 0);
    acc[0] = __builtin_amdgcn_mfma_f32_16x16x32_bf16(ah, bl0, acc[0], 0, 0, 0);
    acc[0] = __builtin_amdgcn_mfma_f32_16x16x32_bf16(al, bh0, acc[0], 0, 0, 0);
    acc[1] = __builtin_amdgcn_mfma_f32_16x16x32_bf16(ah, bh1, acc[1], 0, 0, 0);
    acc[1] = __builtin_amdgcn_mfma_f32_16x16x32_bf16(ah, bl1, acc[1], 0, 0, 0);
    acc[1] = __builtin_amdgcn_mfma_f32_16x16x32_bf16(al, bh1, acc[1], 0, 0, 0);
    __syncthreads();
    if (s < 23) MWSTORE();
    __syncthreads();
  }
#undef MGLOAD
#undef MWSTORE

  // Epilogue: acc -> Wps (+Wp_b, *TS). C layout: col(lane&15)=h-sub, row=fg*4+e=p.
  {
    float* wps = (float*)&Wps4[0][0];
#pragma unroll
    for (int j = 0; j < 2; ++j) {
      int h = n0 + j * 16 + fr;
      float bbv = Wp_b[h];
#pragma unroll
      for (int e = 0; e < 4; ++e) {
        int p = fg * 4 + e;
        wps[p * 132 + h] = (acc[j][e] + bbv) * TS;
      }
    }
  }

  // ---------- Phase B staging: W2s (reduce NZ planes) + vsh ----------
  for (int ff = t; ff < LQ * 32; ff += 256) {
    int q_ = ff % LQ, c4 = ff / LQ;
    const float* pp = &partialW2[(size_t)(q_ * BZ + b) * HH + c4 * 4];
    float4 p0 = *(const float4*)pp;
    float4 p1 = *(const float4*)(pp + (size_t)1600 * HH);
    float4 p2 = *(const float4*)(pp + (size_t)2 * 1600 * HH);
    float4 p3 = *(const float4*)(pp + (size_t)3 * 1600 * HH);
    float4 bb = *(const float4*)&Wq_b[c4 * 4];
    float4 wv = *(const float4*)&Wvv[b * HH + c4 * 4];
    sm.s.W2s[c4 * 4 + 0][q_] = (p0.x + p1.x + p2.x + p3.x + bb.x + wv.x) * TS;
    sm.s.W2s[c4 * 4 + 1][q_] = (p0.y + p1.y + p2.y + p3.y + bb.y + wv.y) * TS;
    sm.s.W2s[c4 * 4 + 2][q_] = (p0.z + p1.z + p2.z + p3.z + bb.z + wv.z) * TS;
    sm.s.W2s[c4 * 4 + 3][q_] = (p0.w + p1.w + p2.w + p3.w + bb.w + wv.w) * TS;
  }
  if (t < 32) *(float4*)&sm.s.vsh[t * 4] = *(const float4*)&v[b * HH + t * 4];
  __syncthreads();

  // ---------- Phase B compute: score + softmax ----------
  const int q = (lane < LQ) ? lane : (LQ - 1);
  const int prow = wid * 4;
  float A0 = 0.f, A1 = 0.f, A2 = 0.f, A3 = 0.f;
  for (int h4 = 0; h4 < 32; ++h4) {
    f32x4 vj = *(const f32x4*)&sm.s.vsh[h4 * 4];
    f32x4 w0 = Wps4[prow + 0][h4];
    f32x4 w1 = Wps4[prow + 1][h4];
    f32x4 w2 = Wps4[prow + 2][h4];
    f32x4 w3 = Wps4[prow + 3][h4];
    float s0 = sm.s.W2s[h4 * 4 + 0][q];
    float s1 = sm.s.W2s[h4 * 4 + 1][q];
    float s2 = sm.s.W2s[h4 * 4 + 2][q];
    float s3 = sm.s.W2s[h4 * 4 + 3][q];
    A0 = fmaf(vj[0], frcp(fexp2(w0[0] + s0) + 1.f), A0);
    A0 = fmaf(vj[1], frcp(fexp2(w0[1] + s1) + 1.f), A0);
    A0 = fmaf(vj[2], frcp(fexp2(w0[2] + s2) + 1.f), A0);
    A0 = fmaf(vj[3], frcp(fexp2(w0[3] + s3) + 1.f), A0);
    A1 = fmaf(vj[0], frcp(fexp2(w1[0] + s0) + 1.f), A1);
    A1 = fmaf(vj[1], frcp(fexp2(w1[1] + s1) + 1.f), A1);
    A1 = fmaf(vj[2], frcp(fexp2(w1[2] + s2) + 1.f), A1);
    A1 = fmaf(vj[3], frcp(fexp2(w1[3] + s3) + 1.f), A1);
    A2 = fmaf(vj[0], frcp(fexp2(w2[0] + s0) + 1.f), A2);
    A2 = fmaf(vj[1], frcp(fexp2(w2[1] + s1) + 1.f), A2);
    A2 = fmaf(vj[2], frcp(fexp2(w2[2] + s2) + 1.f), A2);
    A2 = fmaf(vj[3], frcp(fexp2(w2[3] + s3) + 1.f), A2);
    A3 = fmaf(vj[0], frcp(fexp2(w3[0] + s0) + 1.f), A3);
    A3 = fmaf(vj[1], frcp(fexp2(w3[1] + s1) + 1.f), A3);
    A3 = fmaf(vj[2], frcp(fexp2(w3[2] + s2) + 1.f), A3);
    A3 = fmaf(vj[3], frcp(fexp2(w3[3] + s3) + 1.f), A3);
  }

#define SOFTMAX(AR, PI)                                                   \
  do {                                                                    \
    float a = (lane < LQ) ? (AR) : 1e30f;                                 \
    float mn = a;                                                         \
    mn = fminf(mn, __shfl_xor(mn, 1));  mn = fminf(mn, __shfl_xor(mn, 2)); \
    mn = fminf(mn, __shfl_xor(mn, 4));  mn = fminf(mn, __shfl_xor(mn, 8)); \
    mn = fminf(mn, __shfl_xor(mn, 16)); mn = fminf(mn, __shfl_xor(mn, 32)); \
    float e = fexp2((mn - a) * TS); /* lanes>=50: exp2(-huge)=0 */        \
    float smv = e;                                                        \
    smv += __shfl_xor(smv, 1);  smv += __shfl_xor(smv, 2);                \
    smv += __shfl_xor(smv, 4);  smv += __shfl_xor(smv, 8);                \
    smv += __shfl_xor(smv, 16); smv += __shfl_xor(smv, 32);               \
    float val = e * frcp(smv);                                            \
    if (lane < LQ) sm.s.as_[prow + (PI)][lane] = val;                     \
  } while (0)

  SOFTMAX(A0, 0); SOFTMAX(A1, 1); SOFTMAX(A2, 2); SOFTMAX(A3, 3);
#undef SOFTMAX
  __syncthreads();

  // ---------- Phase C: ctx ----------
  if (t < 192) {
    const int s4 = t * 4;
    f32x4 cacc[16];
#pragma unroll
    for (int i = 0; i < 16; ++i) cacc[i] = (f32x4){0.f, 0.f, 0.f, 0.f};
    for (int qp = 0; qp < LQ; qp += 2) {
      float4 u0 = *(const float4*)&Uq[(size_t)(qp * BZ + b) * SZ + s4];
      float4 u1 = *(const float4*)&Uq[(size_t)((qp + 1) * BZ + b) * SZ + s4];
#pragma unroll
      for (int i = 0; i < 16; ++i) {
        float2 a2 = *(const float2*)&sm.s.as_[i][qp];
        cacc[i][0] = fmaf(a2.x, u0.x, cacc[i][0]); cacc[i][1] = fmaf(a2.x, u0.y, cacc[i][1]);
        cacc[i][2] = fmaf(a2.x, u0.z, cacc[i][2]); cacc[i][3] = fmaf(a2.x, u0.w, cacc[i][3]);
        cacc[i][0] = fmaf(a2.y, u1.x, cacc[i][0]); cacc[i][1] = fmaf(a2.y, u1.y, cacc[i][1]);
        cacc[i][2] = fmaf(a2.y, u1.z, cacc[i][2]); cacc[i][3] = fmaf(a2.y, u1.w, cacc[i][3]);
      }
    }
#pragma unroll
    for (int i = 0; i < 16; ++i) {
      float4 r = make_float4(cacc[i][0], cacc[i][1], cacc[i][2], cacc[i][3]);
      *(float4*)&out[(size_t)((pbase + i) * BZ + b) * SZ + s4] = r;
    }
  }
}

extern "C" void kernel_launch(void* const* d_in, const int* in_sizes, int n_in,
                              void* d_out, int out_size, void* d_ws, size_t ws_size,
                              hipStream_t stream) {
  const float* Up   = (const float*)d_in[0];
  const float* Uq   = (const float*)d_in[1];
  const float* Wp_w = (const float*)d_in[2];
  const float* Wp_b = (const float*)d_in[3];
  const float* Wq_w = (const float*)d_in[4];
  const float* Wq_b = (const float*)d_in[5];
  const float* Wv_w = (const float*)d_in[6];
  const float* Wv_b = (const float*)d_in[7];
  const float* v    = (const float*)d_in[8];
  float* out = (float*)d_out;

  // workspace ~4.1 MB: Wvv + 4 bf16 planes + small Uq-projection partials.
  float* ws        = (float*)d_ws;
  float* Wvv       = ws;                          // 32*128 f
  u16* Wph         = (u16*)(Wvv + BZ * HH);       // 4 planes x 98304 u16
  u16* Wpl         = Wph + HH * SZ;
  u16* Wqh         = Wpl + HH * SZ;
  u16* Wql         = Wqh + HH * SZ;
  float* partialW2 = (float*)(Wql + HH * SZ);     // NZ x 1600 x 128 f = 3.28 MB

  const float TS = 2.8853900817779268f;  // 2*log2(e)

  prep_kernel<<<dim3(112), dim3(256), 0, stream>>>(
      Wp_w, Wq_w, v, Wv_w, Wv_b, Wph, Wpl, Wqh, Wql, Wvv);
  w2_gemm<<<dim3(25, NZ), dim3(256), 0, stream>>>(Uq, Wqh, Wql, partialW2);
  mega_kernel<<<dim3(800), dim3(256), 0, stream>>>(
      Up, Wph, Wpl, partialW2, Wp_b, Wq_b, Wvv, v, Uq, out, TS);
}